// Round 6
// baseline (254.300 us; speedup 1.0000x reference)
//
#include <hip/hip_runtime.h>
#include <stdint.h>

// HashedEmbeddingBag: out[b][d] = sum_{i<50} weight[(idx[b][i]*P1 + d*P2) % WS]
// WS = 2,000,000; B = 16384; L = 50; D = 128.
//
// R15: grid-split hybrid. R14 post-mortem: putting gather waves INSIDE the
// sweep block changed nothing because __syncthreads ties both roles to the
// sweep's per-thread critical path, and 48 bags / 6 groups kept 4
// streams/thread = R12's exact per-thread load. Fix: separate BLOCKS.
//  - 512 blocks, all 1024 thr, all 75.1KB static LDS -> 2 blocks/CU
//    (153.9KB, 32 waves, VGPR<=64 via __launch_bounds__(1024,8)).
//  - blocks 0..255 = SWEEP role: bags [b*64, b*64+48). 24 pairs -> 3
//    streams/thread (0.75x R12 per-thread load -- the actual critical
//    path). Single 56KB bf16 tile, 70 regions, 2 barriers/region;
//    staging drains are covered by the co-resident gather block.
//  - blocks 256..511 = GATHER role: bags [g*64+48, g*64+64) straight from
//    the L2-resident 4MB bf16 table (no sort, no keys, no barriers in the
//    hot loop). thread = (bag = tid>>6, d0 = tid&63), dims {d0, d0+64},
//    50 iters x 2 independent 2B loads; hashes in 3.2KB LDS.
// Dispatch order: sweep blocks fill every CU's first slot, gather blocks
// the second -> 1+1 pairing (perf heuristic only; correctness does not
// depend on placement). Roles share no barriers -> the cross-block slip
// R14 forbade. Per-CU model: sweep LDS ~68us + VALU ~75us vs gather VMEM
// ~43us (102K divergent addrs @ ~1 line/cy L1) -> dur ~130-155us.
// Accuracy: sweep bags = R12's proven pair-order sums (absmax 0.25);
// gather bags sum in exact reference index order. Threshold 0.71.

#define WS       2000000
#define EMB_DIM  128
#define BAG_LEN  50
#define BATCH    16384

#define NBLK     512                    // 256 sweep + 256 gather
#define NBLK_SW  256
#define NTHR     1024
#define BAGS_PB  64
#define SWBAGS   48                     // bags per sweep block
#define NPAIR    24                     // sweep bag-pair streams per block
#define SPT      3                      // sweep streams per thread
#define EXTP     204                    // 100 + 100 rotation + 4 sentinels
#define TILEE    28672                  // tile entries (bf16) = 56KB
#define NREGS    70                     // 69*28672=1,978,368; last 21,632
#define SBIG     300227u                // P2 % WS
#define SENT     0x10000000u            // sentinel key; u stays >= LIM

#define OFF_EXT  57344                  // 24*204*4 = 19584 B keys
#define SMEM_SZ  76928                  // 75.1 KB -> 2 blocks/CU

#define GLOAD_LDS16(gp, lp)                                            \
    __builtin_amdgcn_global_load_lds(                                  \
        (const __attribute__((address_space(1))) uint32_t*)(gp),       \
        (__attribute__((address_space(3))) uint32_t*)(lp), 16, 0, 0)

// ---- pre-pass: fp32 table -> bf16 (round-to-nearest-even) ----
__global__ __launch_bounds__(1024) void conv_bf16(
    const float* __restrict__ w, uint16_t* __restrict__ o)
{
    const int i = (blockIdx.x * 1024 + threadIdx.x) * 4;   // 4 floats/thread
    if (i >= WS) return;
    const float4 f = *(const float4*)(w + i);
    uint32_t u0 = __float_as_uint(f.x), u1 = __float_as_uint(f.y);
    uint32_t u2 = __float_as_uint(f.z), u3 = __float_as_uint(f.w);
    ushort4 r;
    r.x = (uint16_t)((u0 + 0x7FFFu + ((u0 >> 16) & 1u)) >> 16);
    r.y = (uint16_t)((u1 + 0x7FFFu + ((u1 >> 16) & 1u)) >> 16);
    r.z = (uint16_t)((u2 + 0x7FFFu + ((u2 >> 16) & 1u)) >> 16);
    r.w = (uint16_t)((u3 + 0x7FFFu + ((u3 >> 16) & 1u)) >> 16);
    *(ushort4*)(o + i) = r;
}

__global__ __launch_bounds__(NTHR, 8) void heb_bf16(
    const uint16_t* __restrict__ wbf,
    const int*      __restrict__ indices,
    float*          __restrict__ out)
{
    __shared__ __align__(16) uint8_t smem[SMEM_SZ];
    const int tid = threadIdx.x;

    if (blockIdx.x >= NBLK_SW) {
        // ================= GATHER role =================
        const int gi   = blockIdx.x - NBLK_SW;
        const int bagL = tid >> 6;               // 0..15
        const int d0   = tid & 63;
        uint32_t* ag = (uint32_t*)smem;          // [16][50] hashes

        for (int p = tid; p < 16 * BAG_LEN; p += NTHR) {
            int b = p / 50, i = p - b * 50;
            uint64_t idx = (uint64_t)(uint32_t)
                indices[(gi * BAGS_PB + SWBAGS + b) * BAG_LEN + i];
            ag[p] = (uint32_t)((idx * 9824516537ull) % (uint64_t)WS);
        }
        __syncthreads();

        const uint32_t c0 = ((uint32_t)d0 * SBIG) % (uint32_t)WS;
        const uint32_t c1 = ((uint32_t)(d0 + 64) * SBIG) % (uint32_t)WS;
        const uint32_t* agb = ag + bagL * BAG_LEN;
        float a0 = 0.0f, a1 = 0.0f;
#pragma unroll 10
        for (int i = 0; i < BAG_LEN; ++i) {
            const uint32_t a = agb[i];           // LDS broadcast
            uint32_t u0 = a + c0; u0 = (u0 >= (uint32_t)WS) ? u0 - WS : u0;
            uint32_t u1 = a + c1; u1 = (u1 >= (uint32_t)WS) ? u1 - WS : u1;
            const uint32_t r0 = (uint32_t)wbf[u0];   // L2-resident gather
            const uint32_t r1 = (uint32_t)wbf[u1];
            a0 += __uint_as_float(r0 << 16);
            a1 += __uint_as_float(r1 << 16);
        }
        const size_t ob =
            (size_t)(gi * BAGS_PB + SWBAGS + bagL) * EMB_DIM;
        out[ob + d0]      = a0;
        out[ob + d0 + 64] = a1;
        return;
    }

    // ================= SWEEP role =================
    const int d       = tid & 127;
    const int g       = tid >> 7;          // group 0..7 (pairs 3g..3g+2)
    const int bagBase = blockIdx.x * BAGS_PB;

    uint16_t* tile0 = (uint16_t*)&smem[0];
    uint32_t* ext   = (uint32_t*)&smem[OFF_EXT];
    // sort scratch in tile (dead before region-0 staging)
    uint32_t* araw  = (uint32_t*)&smem[0];        // [48][52]
    uint32_t* S     = (uint32_t*)&smem[9984];     // [48][52]

    // ---- phase 1: sentinel-fill ext; hash a = idx*P1 % WS ----
    for (int p = tid; p < NPAIR * EXTP; p += NTHR) ext[p] = SENT;
    for (int p = tid; p < SWBAGS * BAG_LEN; p += NTHR) {
        uint32_t b = (uint32_t)p / 50u;
        uint32_t i = (uint32_t)p - b * 50u;
        uint64_t idx = (uint64_t)(uint32_t)
            indices[bagBase * BAG_LEN + p];
        araw[b * 52 + i] = (uint32_t)((idx * 9824516537ull) % (uint64_t)WS);
    }
    __syncthreads();

    // ---- phase 2a: rank-sort each bag (ties by index) -> S ----
    for (int p = tid; p < SWBAGS * BAG_LEN; p += NTHR) {
        uint32_t b = (uint32_t)p / 50u;
        uint32_t i = (uint32_t)p - b * 50u;
        uint32_t v = araw[b * 52 + i];
        int rank = 0;
        for (int q = 0; q < BAG_LEN; ++q) {
            uint32_t w = araw[b * 52 + q];
            rank += (w < v || (w == v && q < (int)i)) ? 1 : 0;
        }
        S[b * 52 + rank] = v;
    }
    __syncthreads();

    // ---- phase 2b: 2-way merge per pair via one binary search ----
    for (int p = tid; p < SWBAGS * BAG_LEN; p += NTHR) {
        uint32_t bag = (uint32_t)p / 50u;
        uint32_t i   = (uint32_t)p - bag * 50u;
        uint32_t pr  = bag >> 1, b = bag & 1u;
        uint32_t v = S[bag * 52 + i];
        const uint32_t* T = &S[(bag ^ 1u) * 52];
        uint32_t key = b ? v + 1u : v;         // tie-break by bag id
        int lo = 0, hi = 50;
        while (lo < hi) {                      // ~6 uniform steps
            int mid = (lo + hi) >> 1;
            bool lt = T[mid] < key;
            lo = lt ? mid + 1 : lo;
            hi = lt ? hi : mid;
        }
        uint32_t* eo = ext + pr * EXTP;
        int rk = (int)i + lo;
        eo[rk]       = (v << 1) | b;                    // first copy
        eo[rk + 100] = ((v + (uint32_t)WS) << 1) | b;   // rotation copy
    }
    __syncthreads();                       // ext final; scratch dead

    // ---- phase 3: per-thread 3-stream init (word-index state) ----
    const uint32_t c  = ((uint32_t)d * SBIG) % (uint32_t)WS;
    const uint32_t C2 = (uint32_t)(((int)c - WS) * 2);  // 2*(c-WS) mod 2^32
    const uint32_t limit2 = ((uint32_t)WS - c) << 1;    // keys < 2*(WS-c)

    uint32_t kq4[SPT], K4[SPT];
    float    s0r[SPT], s1r[SPT];
#pragma unroll
    for (int qi = 0; qi < SPT; ++qi) {
        const uint32_t rbase = (uint32_t)(g * SPT + qi) * EXTP;
        int lo = 0, hi = 100;
        while (lo < hi) {
            int mid = (lo + hi) >> 1;
            bool lt = ext[rbase + (uint32_t)mid] < limit2;
            lo = lt ? mid + 1 : lo;
            hi = lt ? hi : mid;
        }
        kq4[qi] = rbase + (uint32_t)lo;    // absolute word index into ext
        K4[qi]  = ext[rbase + (uint32_t)lo];
        s0r[qi] = 0.0f; s1r[qi] = 0.0f;
    }

    // ---- phase 4: region sweep, single 56KB tile, 2 barriers/region ----
    for (int r = 0; r < NREGS; ++r) {
        const int rlo = r * TILEE;
        const int len = (TILEE < WS - rlo) ? TILEE : (WS - rlo);

        __syncthreads();                   // prev region consumed
        for (int s = tid; s < (len >> 3); s += NTHR)
            GLOAD_LDS16(wbf + rlo + (s << 3), tile0 + (s << 3));
        __syncthreads();                   // barrier drains vmcnt

        const uint32_t CLr = C2 - ((uint32_t)rlo << 1);
        const uint32_t LIM = (uint32_t)len << 1;

#pragma unroll
        for (int qi = 0; qi < SPT; ++qi) {
            uint32_t kq = kq4[qi], K = K4[qi];
            float s0 = s0r[qi], s1 = s1r[qi];
            uint32_t u = K + CLr;          // 2*(pos-rlo) + tag
            while (u < LIM) {
                const uint32_t raw =
                    *(const uint16_t*)(smem + (u & ~1u)); // ds_read_u16
                K = ext[kq + 1u];                  // next key early
                ++kq;
                const float v = __uint_as_float(raw << 16);
                const bool odd = (u & 1u) != 0u;   // 1-bit routing
                s0 += odd ? 0.0f : v;
                s1 += odd ? v : 0.0f;
                u = K + CLr;
            }
            kq4[qi] = kq; K4[qi] = K;
            s0r[qi] = s0; s1r[qi] = s1;
        }
    }

    // ---- phase 5: output straight from registers (bag = 6g + 2qi + t) ----
#pragma unroll
    for (int qi = 0; qi < SPT; ++qi) {
        const int bag = g * 6 + (qi << 1);
        out[(size_t)(bagBase + bag) * EMB_DIM + d]     = s0r[qi];
        out[(size_t)(bagBase + bag + 1) * EMB_DIM + d] = s1r[qi];
    }
}

// ---- fallback (ws too small): R7's proven fp32 single-tile kernel ----
#define RSIZE_FB 32768
#define NREG_FB  62
#define EXT_N    104
#define SENT4    0x10000000u

__global__ __launch_bounds__(NTHR, 4) void heb_single(
    const float* __restrict__ weight,
    const int*   __restrict__ indices,
    float*       __restrict__ out)
{
    __shared__ __align__(16) float tile[RSIZE_FB];
    __shared__ uint32_t ext4[BAGS_PB][EXT_N];
    const int tid = threadIdx.x, d = tid & 127, bag_lo = tid >> 7;
    const int bagBase = blockIdx.x * BAGS_PB;
    uint32_t* araw = (uint32_t*)&tile[0];
    for (int p = tid; p < BAGS_PB * BAG_LEN; p += NTHR) {
        uint32_t g = (uint32_t)p / 50u, i = (uint32_t)p - g * 50u;
        uint64_t idx = (uint64_t)(uint32_t)indices[bagBase * BAG_LEN + p];
        araw[g * 52 + i] = (uint32_t)((idx * 9824516537ull) % (uint64_t)WS);
    }
    __syncthreads();
    for (int p = tid; p < BAGS_PB * BAG_LEN; p += NTHR) {
        uint32_t g = (uint32_t)p / 50u, i = (uint32_t)p - g * 50u;
        uint32_t v = araw[g * 52 + i];
        int rank = 0;
        for (int q = 0; q < BAG_LEN; ++q) {
            uint32_t w = araw[g * 52 + q];
            rank += (w < v || (w == v && q < (int)i)) ? 1 : 0;
        }
        ext4[g][rank] = v << 2;
        ext4[g][rank + 50] = (v + (uint32_t)WS) << 2;
    }
    for (int p = tid; p < BAGS_PB * 4; p += NTHR)
        ext4[p >> 2][100 + (p & 3)] = SENT4;
    __syncthreads();
    const uint32_t c = ((uint32_t)d * SBIG) % (uint32_t)WS;
    const uint32_t C4 = (uint32_t)(((int)c - WS) * 4);
    const uint32_t wmc4 = ((uint32_t)WS - c) << 2;
    uint32_t t4[8], h4[8]; float sm[8];
#pragma unroll
    for (int k = 0; k < 8; ++k) {
        const uint32_t* eg = &ext4[(bag_lo << 3) + k][0];
        int nlow = 0;
        for (int q = 0; q < BAG_LEN; ++q) nlow += (eg[q] < wmc4) ? 1 : 0;
        t4[k] = (uint32_t)nlow << 2; h4[k] = eg[nlow] + C4; sm[k] = 0.0f;
    }
    for (int r = 0; r < NREG_FB; ++r) {
        const int lo = r * RSIZE_FB;
        const int len = (RSIZE_FB < WS - lo) ? RSIZE_FB : (WS - lo);
        __syncthreads();
        for (int s = tid; s < (len >> 2); s += NTHR)
            GLOAD_LDS16(weight + lo + (s << 2), &tile[s << 2]);
        __syncthreads();
        const uint32_t lo4 = ((uint32_t)lo) << 2;
        const uint32_t hi4 = (r == NREG_FB - 1) ? (uint32_t)(4 * WS)
                                                : lo4 + ((uint32_t)RSIZE_FB << 2);
        const char* tb = (const char*)&tile[0];
#pragma unroll
        for (int k = 0; k < 8; ++k) {
            const char* eg = (const char*)&ext4[(bag_lo << 3) + k][0];
            uint32_t t_ = t4[k], h_ = h4[k]; float s_ = sm[k];
            while (h_ < hi4) {
                s_ += *(const float*)(tb + (h_ - lo4));
                t_ += 4u;
                h_ = *(const uint32_t*)(eg + t_) + C4;
            }
            t4[k] = t_; h4[k] = h_; sm[k] = s_;
        }
    }
#pragma unroll
    for (int k = 0; k < 8; ++k)
        out[(size_t)(bagBase + (bag_lo << 3) + k) * EMB_DIM + d] = sm[k];
}

extern "C" void kernel_launch(void* const* d_in, const int* in_sizes, int n_in,
                              void* d_out, int out_size, void* d_ws, size_t ws_size,
                              hipStream_t stream)
{
    const float* weight  = (const float*)d_in[0];   // [2,000,000] fp32
    const int*   indices = (const int*)d_in[1];     // [16384*50] int
    float*       out     = (float*)d_out;           // [16384*128] fp32

    if (ws_size >= (size_t)WS * sizeof(uint16_t)) {
        uint16_t* wbf = (uint16_t*)d_ws;
        conv_bf16<<<(WS / 4 + 1023) / 1024, 1024, 0, stream>>>(weight, wbf);
        heb_bf16<<<NBLK, NTHR, 0, stream>>>(wbf, indices, out);
    } else {
        heb_single<<<NBLK, NTHR, 0, stream>>>(weight, indices, out);
    }
}

// Round 7
// 210.487 us; speedup vs baseline: 1.2082x; 1.2082x over previous
//
#include <hip/hip_runtime.h>
#include <stdint.h>

// HashedEmbeddingBag: out[b][d] = sum_{i<50} weight[(idx[b][i]*P1 + d*P2) % WS]
// WS = 2,000,000; B = 16384; L = 50; D = 128.
//
// R16: TLP experiment -- 2 co-resident sweep blocks per CU, same loop.
// Evidence trail: R9/R12/R13 (177/181/183) have 1.5x different per-element
// op counts yet identical dur -> not issue-bound on either pipe alone.
// R13's "unroll-2 ILP" added NO real ILP (key-pair ds_read sits in series
// with the gathers: 2 LDS round-trips per 2 elements = R12's per-element
// latency) -> latency-bound hypothesis UNFALSIFIED. Every round so far ran
// 4 waves/SIMD (157KB LDS -> 1 block/CU). This round changes ONLY wave
// parallelism: per-SIMD issue volume is identical to R12 (8 waves x 657
// iters = 4 x 1314).
//  - 512 blocks x 32 bags. 16 pairs/block, SPT=2 streams/thread (100 keys
//    each). Inner loop byte-identical to R12's (proven, absmax 0.25).
//  - single 64KB tile (32768 entries, 62 regions, 2 barriers/region) +
//    13KB keys = 76.8KB -> 2 blocks/CU (153.5KB), 32 waves, 8/SIMD.
//    __launch_bounds__(1024,8) caps VGPR at 64 (kernel uses ~45).
//  - staging exposure per block is covered by the SIBLING block's compute
//    (symmetric roles -- nobody idles after retiring, unlike R15).
//  - staging L2 traffic doubles to 8MB/CU (~13TB/s aggregate, well under
//    34.5TB/s L2 ceiling).
// Prediction: latency-bound -> 125-150us, VALU 75-90%, occ ~85%.
// Issue-bound -> flat ~180 at occ ~85% (decisive falsifier; then only
// asm-level op surgery remains).
// Accuracy: same bf16 RNE table, same pair-order register sums as R12.

#define WS       2000000
#define EMB_DIM  128
#define BAG_LEN  50
#define BATCH    16384

#define NBLK     512
#define NTHR     1024
#define BPB      32                     // bags per block
#define NPAIR    16                     // bag-pair streams per block
#define SPT      2                      // streams per thread
#define EXTP     204                    // 100 + 100 rotation + 4 sentinels
#define TILEE    32768                  // tile entries (bf16) = 64KB
#define NREGS    62                     // 61*32768=1,998,848; last 1152
#define SBIG     300227u                // P2 % WS
#define SENT     0x10000000u            // sentinel key; u stays >= LIM

#define OFF_EXT  65536                  // 16*204*4 = 13056 B keys
#define SMEM_SZ  78592                  // 76.75 KB -> 2 blocks/CU

#define GLOAD_LDS16(gp, lp)                                            \
    __builtin_amdgcn_global_load_lds(                                  \
        (const __attribute__((address_space(1))) uint32_t*)(gp),       \
        (__attribute__((address_space(3))) uint32_t*)(lp), 16, 0, 0)

// ---- pre-pass: fp32 table -> bf16 (round-to-nearest-even) ----
__global__ __launch_bounds__(1024) void conv_bf16(
    const float* __restrict__ w, uint16_t* __restrict__ o)
{
    const int i = (blockIdx.x * 1024 + threadIdx.x) * 4;   // 4 floats/thread
    if (i >= WS) return;
    const float4 f = *(const float4*)(w + i);
    uint32_t u0 = __float_as_uint(f.x), u1 = __float_as_uint(f.y);
    uint32_t u2 = __float_as_uint(f.z), u3 = __float_as_uint(f.w);
    ushort4 r;
    r.x = (uint16_t)((u0 + 0x7FFFu + ((u0 >> 16) & 1u)) >> 16);
    r.y = (uint16_t)((u1 + 0x7FFFu + ((u1 >> 16) & 1u)) >> 16);
    r.z = (uint16_t)((u2 + 0x7FFFu + ((u2 >> 16) & 1u)) >> 16);
    r.w = (uint16_t)((u3 + 0x7FFFu + ((u3 >> 16) & 1u)) >> 16);
    *(ushort4*)(o + i) = r;
}

__global__ __launch_bounds__(NTHR, 8) void heb_bf16(
    const uint16_t* __restrict__ wbf,
    const int*      __restrict__ indices,
    float*          __restrict__ out)
{
    __shared__ __align__(16) uint8_t smem[SMEM_SZ];

    const int tid     = threadIdx.x;
    const int d       = tid & 127;
    const int g       = tid >> 7;          // group 0..7 (pairs 2g, 2g+1)
    const int bagBase = blockIdx.x * BPB;

    uint16_t* tile0 = (uint16_t*)&smem[0];
    uint32_t* ext   = (uint32_t*)&smem[OFF_EXT];
    // sort scratch in tile region (dead before region-0 staging, which
    // happens only after the phase-3 barrier)
    uint32_t* araw  = (uint32_t*)&smem[0];        // [32][52] = 6656 B
    uint32_t* S     = (uint32_t*)&smem[6656];     // [32][52]

    // ---- phase 1: sentinel-fill ext; hash a = idx*P1 % WS ----
    for (int p = tid; p < NPAIR * EXTP; p += NTHR) ext[p] = SENT;
    for (int p = tid; p < BPB * BAG_LEN; p += NTHR) {
        uint32_t b = (uint32_t)p / 50u;
        uint32_t i = (uint32_t)p - b * 50u;
        uint64_t idx = (uint64_t)(uint32_t)
            indices[bagBase * BAG_LEN + p];
        araw[b * 52 + i] = (uint32_t)((idx * 9824516537ull) % (uint64_t)WS);
    }
    __syncthreads();

    // ---- phase 2a: rank-sort each bag (ties by index) -> S ----
    for (int p = tid; p < BPB * BAG_LEN; p += NTHR) {
        uint32_t b = (uint32_t)p / 50u;
        uint32_t i = (uint32_t)p - b * 50u;
        uint32_t v = araw[b * 52 + i];
        int rank = 0;
        for (int q = 0; q < BAG_LEN; ++q) {
            uint32_t w = araw[b * 52 + q];
            rank += (w < v || (w == v && q < (int)i)) ? 1 : 0;
        }
        S[b * 52 + rank] = v;
    }
    __syncthreads();

    // ---- phase 2b: 2-way merge per pair via one binary search ----
    for (int p = tid; p < BPB * BAG_LEN; p += NTHR) {
        uint32_t bag = (uint32_t)p / 50u;
        uint32_t i   = (uint32_t)p - bag * 50u;
        uint32_t pr  = bag >> 1, b = bag & 1u;
        uint32_t v = S[bag * 52 + i];
        const uint32_t* T = &S[(bag ^ 1u) * 52];
        uint32_t key = b ? v + 1u : v;         // tie-break by bag id
        int lo = 0, hi = 50;
        while (lo < hi) {                      // ~6 uniform steps
            int mid = (lo + hi) >> 1;
            bool lt = T[mid] < key;
            lo = lt ? mid + 1 : lo;
            hi = lt ? hi : mid;
        }
        uint32_t* eo = ext + pr * EXTP;
        int rk = (int)i + lo;
        eo[rk]       = (v << 1) | b;                    // first copy
        eo[rk + 100] = ((v + (uint32_t)WS) << 1) | b;   // rotation copy
    }
    __syncthreads();                       // ext final; scratch dead

    // ---- phase 3: per-thread 2-stream init (word-index state) ----
    const uint32_t c  = ((uint32_t)d * SBIG) % (uint32_t)WS;
    const uint32_t C2 = (uint32_t)(((int)c - WS) * 2);  // 2*(c-WS) mod 2^32
    const uint32_t limit2 = ((uint32_t)WS - c) << 1;    // keys < 2*(WS-c)

    uint32_t kq4[SPT], K4[SPT];
    float    s0r[SPT], s1r[SPT];
#pragma unroll
    for (int qi = 0; qi < SPT; ++qi) {
        const uint32_t rbase = (uint32_t)(g * SPT + qi) * EXTP;
        int lo = 0, hi = 100;
        while (lo < hi) {
            int mid = (lo + hi) >> 1;
            bool lt = ext[rbase + (uint32_t)mid] < limit2;
            lo = lt ? mid + 1 : lo;
            hi = lt ? hi : mid;
        }
        kq4[qi] = rbase + (uint32_t)lo;    // absolute word index into ext
        K4[qi]  = ext[rbase + (uint32_t)lo];
        s0r[qi] = 0.0f; s1r[qi] = 0.0f;
    }

    // ---- phase 4: region sweep, single 64KB tile, 2 barriers/region ----
    for (int r = 0; r < NREGS; ++r) {
        const int rlo = r * TILEE;
        const int len = (TILEE < WS - rlo) ? TILEE : (WS - rlo);

        __syncthreads();                   // prev region consumed
        for (int s = tid; s < (len >> 3); s += NTHR)
            GLOAD_LDS16(wbf + rlo + (s << 3), tile0 + (s << 3));
        __syncthreads();                   // barrier drains vmcnt

        const uint32_t CLr = C2 - ((uint32_t)rlo << 1);
        const uint32_t LIM = (uint32_t)len << 1;

#pragma unroll
        for (int qi = 0; qi < SPT; ++qi) {
            uint32_t kq = kq4[qi], K = K4[qi];
            float s0 = s0r[qi], s1 = s1r[qi];
            uint32_t u = K + CLr;          // 2*(pos-rlo) + tag
            while (u < LIM) {
                const uint32_t raw =
                    *(const uint16_t*)(smem + (u & ~1u)); // ds_read_u16
                K = ext[kq + 1u];                  // next key early
                ++kq;
                const float v = __uint_as_float(raw << 16);
                const bool odd = (u & 1u) != 0u;   // 1-bit routing
                s0 += odd ? 0.0f : v;
                s1 += odd ? v : 0.0f;
                u = K + CLr;
            }
            kq4[qi] = kq; K4[qi] = K;
            s0r[qi] = s0; s1r[qi] = s1;
        }
    }

    // ---- phase 5: output straight from registers (bag = 4g + 2qi + t) ----
#pragma unroll
    for (int qi = 0; qi < SPT; ++qi) {
        const int bag = (g << 2) + (qi << 1);
        out[(size_t)(bagBase + bag) * EMB_DIM + d]     = s0r[qi];
        out[(size_t)(bagBase + bag + 1) * EMB_DIM + d] = s1r[qi];
    }
}

// ---- fallback (ws too small): R7's proven fp32 single-tile kernel ----
#define BAGS_FB  64
#define RSIZE_FB 32768
#define NREG_FB  62
#define EXT_N    104
#define SENT4    0x10000000u

__global__ __launch_bounds__(NTHR, 4) void heb_single(
    const float* __restrict__ weight,
    const int*   __restrict__ indices,
    float*       __restrict__ out)
{
    __shared__ __align__(16) float tile[RSIZE_FB];
    __shared__ uint32_t ext4[BAGS_FB][EXT_N];
    const int tid = threadIdx.x, d = tid & 127, bag_lo = tid >> 7;
    const int bagBase = blockIdx.x * BAGS_FB;
    uint32_t* araw = (uint32_t*)&tile[0];
    for (int p = tid; p < BAGS_FB * BAG_LEN; p += NTHR) {
        uint32_t g = (uint32_t)p / 50u, i = (uint32_t)p - g * 50u;
        uint64_t idx = (uint64_t)(uint32_t)indices[bagBase * BAG_LEN + p];
        araw[g * 52 + i] = (uint32_t)((idx * 9824516537ull) % (uint64_t)WS);
    }
    __syncthreads();
    for (int p = tid; p < BAGS_FB * BAG_LEN; p += NTHR) {
        uint32_t g = (uint32_t)p / 50u, i = (uint32_t)p - g * 50u;
        uint32_t v = araw[g * 52 + i];
        int rank = 0;
        for (int q = 0; q < BAG_LEN; ++q) {
            uint32_t w = araw[g * 52 + q];
            rank += (w < v || (w == v && q < (int)i)) ? 1 : 0;
        }
        ext4[g][rank] = v << 2;
        ext4[g][rank + 50] = (v + (uint32_t)WS) << 2;
    }
    for (int p = tid; p < BAGS_FB * 4; p += NTHR)
        ext4[p >> 2][100 + (p & 3)] = SENT4;
    __syncthreads();
    const uint32_t c = ((uint32_t)d * SBIG) % (uint32_t)WS;
    const uint32_t C4 = (uint32_t)(((int)c - WS) * 4);
    const uint32_t wmc4 = ((uint32_t)WS - c) << 2;
    uint32_t t4[8], h4[8]; float sm[8];
#pragma unroll
    for (int k = 0; k < 8; ++k) {
        const uint32_t* eg = &ext4[(bag_lo << 3) + k][0];
        int nlow = 0;
        for (int q = 0; q < BAG_LEN; ++q) nlow += (eg[q] < wmc4) ? 1 : 0;
        t4[k] = (uint32_t)nlow << 2; h4[k] = eg[nlow] + C4; sm[k] = 0.0f;
    }
    for (int r = 0; r < NREG_FB; ++r) {
        const int lo = r * RSIZE_FB;
        const int len = (RSIZE_FB < WS - lo) ? RSIZE_FB : (WS - lo);
        __syncthreads();
        for (int s = tid; s < (len >> 2); s += NTHR)
            GLOAD_LDS16(weight + lo + (s << 2), &tile[s << 2]);
        __syncthreads();
        const uint32_t lo4 = ((uint32_t)lo) << 2;
        const uint32_t hi4 = (r == NREG_FB - 1) ? (uint32_t)(4 * WS)
                                                : lo4 + ((uint32_t)RSIZE_FB << 2);
        const char* tb = (const char*)&tile[0];
#pragma unroll
        for (int k = 0; k < 8; ++k) {
            const char* eg = (const char*)&ext4[(bag_lo << 3) + k][0];
            uint32_t t_ = t4[k], h_ = h4[k]; float s_ = sm[k];
            while (h_ < hi4) {
                s_ += *(const float*)(tb + (h_ - lo4));
                t_ += 4u;
                h_ = *(const uint32_t*)(eg + t_) + C4;
            }
            t4[k] = t_; h4[k] = h_; sm[k] = s_;
        }
    }
#pragma unroll
    for (int k = 0; k < 8; ++k)
        out[(size_t)(bagBase + (bag_lo << 3) + k) * EMB_DIM + d] = sm[k];
}

extern "C" void kernel_launch(void* const* d_in, const int* in_sizes, int n_in,
                              void* d_out, int out_size, void* d_ws, size_t ws_size,
                              hipStream_t stream)
{
    const float* weight  = (const float*)d_in[0];   // [2,000,000] fp32
    const int*   indices = (const int*)d_in[1];     // [16384*50] int
    float*       out     = (float*)d_out;           // [16384*128] fp32

    if (ws_size >= (size_t)WS * sizeof(uint16_t)) {
        uint16_t* wbf = (uint16_t*)d_ws;
        conv_bf16<<<(WS / 4 + 1023) / 1024, 1024, 0, stream>>>(weight, wbf);
        heb_bf16<<<NBLK, NTHR, 0, stream>>>(wbf, indices, out);
    } else {
        heb_single<<<256, NTHR, 0, stream>>>(weight, indices, out);
    }
}